// Round 1
// baseline (4175.959 us; speedup 1.0000x reference)
//
#include <hip/hip_runtime.h>

#define D256 256
#define ALEN 128
#define INDIM 512
#define BSZ 32
#define TLEN 2048
#define CHL 32     // chunk length
#define NCH 64     // number of chunks
#define ROWS 2048  // NCH * BSZ

__device__ __forceinline__ float leakyf(float x)  { return x < 0.f ? 0.01f * x : x; }
__device__ __forceinline__ float ileakyf(float x) { return x < 0.f ? x * (1.0f / 0.01f) : x; }

// ---------------------------------------------------------------------------
// 256x256 transpose (out[d][e] = in[e][d])
// ---------------------------------------------------------------------------
__global__ __launch_bounds__(256) void transpose256(const float* __restrict__ in,
                                                    float* __restrict__ out) {
  __shared__ float t[32][33];
  const int lx = threadIdx.x, ly = threadIdx.y;
  const int bx = blockIdx.x * 32, by = blockIdx.y * 32;
#pragma unroll
  for (int i = 0; i < 4; ++i)
    t[ly + 8 * i][lx] = in[(size_t)(by + ly + 8 * i) * 256 + bx + lx];
  __syncthreads();
#pragma unroll
  for (int i = 0; i < 4; ++i)
    out[(size_t)(bx + ly + 8 * i) * 256 + by + lx] = t[lx][ly + 8 * i];
}

// ---------------------------------------------------------------------------
// Encoder, t=0 only: z0 = leaky(We2 @ leaky(We1 @ x0 + be1) + be2)
// grid = 32 (batch), block = 256 (e)
// ---------------------------------------------------------------------------
__global__ __launch_bounds__(256) void encoder_kernel(
    const float* __restrict__ in, const float* __restrict__ We1,
    const float* __restrict__ be1, const float* __restrict__ We2,
    const float* __restrict__ be2, float* __restrict__ z0) {
  const int b = blockIdx.x, e = threadIdx.x;
  __shared__ float xb[256];
  __shared__ float h1[256];
  xb[e] = in[(size_t)b * TLEN * INDIM + e];
  __syncthreads();
  float acc = be1[e];
  const float4* w = (const float4*)(We1 + (size_t)e * 256);
#pragma unroll 8
  for (int d4 = 0; d4 < 64; ++d4) {
    float4 wv = w[d4];
    acc += wv.x * xb[4 * d4] + wv.y * xb[4 * d4 + 1] + wv.z * xb[4 * d4 + 2] + wv.w * xb[4 * d4 + 3];
  }
  h1[e] = leakyf(acc);
  __syncthreads();
  float a2 = be2[e];
  w = (const float4*)(We2 + (size_t)e * 256);
#pragma unroll 8
  for (int d4 = 0; d4 < 64; ++d4) {
    float4 wv = w[d4];
    a2 += wv.x * h1[4 * d4] + wv.y * h1[4 * d4 + 1] + wv.z * h1[4 * d4 + 2] + wv.w * h1[4 * d4 + 3];
  }
  z0[(size_t)b * 256 + e] = leakyf(a2);
}

// ---------------------------------------------------------------------------
// Generic fp32 GEMM: Out[m][n] = sum_k In[m][k] * W[n][k] (+bias1[n]+bias2[n], act)
// N = 256 global, Out row stride 256. BM=BN=128, BK=32, 8x8 micro per thread.
// grid = (M/128, 2). act: 0 none, 1 leaky, 2 inv_leaky.
// LDS slot-XOR swizzle (float4 granularity) keeps both staging stores and
// fragment reads bank-conflict-free.
// ---------------------------------------------------------------------------
__global__ __launch_bounds__(256) void gemm_tn(
    const float* __restrict__ In, int in_stride, int in_off,
    const float* __restrict__ W, int K,
    const float* __restrict__ bias1, const float* __restrict__ bias2,
    int act, float* __restrict__ Out) {
  __shared__ float a_lds[128][32];
  __shared__ float b_lds[128][32];
  const int tid = threadIdx.x;
  const int tm = tid >> 4, tn = tid & 15;
  const int m0 = blockIdx.x * 128, n0 = blockIdx.y * 128;
  float acc[8][8];
#pragma unroll
  for (int i = 0; i < 8; ++i)
#pragma unroll
    for (int j = 0; j < 8; ++j) acc[i][j] = 0.f;

  for (int kb = 0; kb < K; kb += 32) {
    __syncthreads();
#pragma unroll
    for (int q = 0; q < 4; ++q) {
      const int idx = q * 256 + tid;
      const int row = idx >> 3, s = idx & 7;
      const int phys = (s ^ ((row >> 3) & 7)) << 2;
      *(float4*)&a_lds[row][phys] =
          *(const float4*)&In[(size_t)(m0 + row) * in_stride + in_off + kb + s * 4];
      *(float4*)&b_lds[row][phys] =
          *(const float4*)&W[(size_t)(n0 + row) * K + kb + s * 4];
    }
    __syncthreads();
#pragma unroll
    for (int k4 = 0; k4 < 8; ++k4) {
      float4 a4[8], b4[8];
      const int pa = (k4 ^ (tm & 7)) << 2;
      const int pb = (k4 ^ (tn & 7)) << 2;
#pragma unroll
      for (int i = 0; i < 8; ++i) a4[i] = *(const float4*)&a_lds[tm * 8 + i][pa];
#pragma unroll
      for (int j = 0; j < 8; ++j) b4[j] = *(const float4*)&b_lds[tn * 8 + j][pb];
#pragma unroll
      for (int i = 0; i < 8; ++i)
#pragma unroll
        for (int j = 0; j < 8; ++j)
          acc[i][j] += a4[i].x * b4[j].x + a4[i].y * b4[j].y +
                       a4[i].z * b4[j].z + a4[i].w * b4[j].w;
    }
  }

  float bsum[8];
#pragma unroll
  for (int j = 0; j < 8; ++j) {
    const int n = n0 + tn * 8 + j;
    float bv = 0.f;
    if (bias1) bv += bias1[n];
    if (bias2) bv += bias2[n];
    bsum[j] = bv;
  }
#pragma unroll
  for (int i = 0; i < 8; ++i) {
    const int m = m0 + tm * 8 + i;
    float o[8];
#pragma unroll
    for (int j = 0; j < 8; ++j) {
      float v = acc[i][j] + bsum[j];
      if (act == 1) v = leakyf(v);
      else if (act == 2) v = ileakyf(v);
      o[j] = v;
    }
    *(float4*)&Out[(size_t)m * 256 + n0 + tn * 8]     = make_float4(o[0], o[1], o[2], o[3]);
    *(float4*)&Out[(size_t)m * 256 + n0 + tn * 8 + 4] = make_float4(o[4], o[5], o[6], o[7]);
  }
}

// ---------------------------------------------------------------------------
// Chunked-scan phase kernel. 2048 independent rows (chunk k, batch b), 8 per
// block, 256 blocks. Each block iterates the 32 in-chunk steps with the carry
// double-buffered in LDS; A^T streamed from L2 (coalesced). Phase1: Einit =
// null (zero init), writes Lend. Phase3: Einit = E array, writes
// w1 = inv_leaky(s_t) every step.
// ---------------------------------------------------------------------------
__global__ __launch_bounds__(256) void phase_kernel(
    const float* __restrict__ AT, const float* __restrict__ Cbuf,
    const float* __restrict__ Einit, float* __restrict__ Lend,
    float* __restrict__ w1out) {
  const int tid = threadIdx.x;
  const int r = tid >> 5, cg = tid & 31, e0 = cg << 3;
  const int rho0 = blockIdx.x << 3;
  const int k = rho0 >> 5;
  const int b = (rho0 & 31) + r;
  __shared__ float carry[2][8][268];

  if (Einit) {
    *(float4*)&carry[0][r][e0]     = *(const float4*)&Einit[(size_t)(rho0 + r) * 256 + e0];
    *(float4*)&carry[0][r][e0 + 4] = *(const float4*)&Einit[(size_t)(rho0 + r) * 256 + e0 + 4];
  } else {
    *(float4*)&carry[0][r][e0]     = make_float4(0.f, 0.f, 0.f, 0.f);
    *(float4*)&carry[0][r][e0 + 4] = make_float4(0.f, 0.f, 0.f, 0.f);
  }
  __syncthreads();

  int buf = 0;
  const float* Crow = Cbuf + ((size_t)b * TLEN + (size_t)k * CHL) * 256;
  float* Wrow = w1out ? w1out + ((size_t)b * TLEN + (size_t)k * CHL) * 256 : (float*)0;
  float acc[8];

  for (int j = 0; j < CHL; ++j) {
    const float4 c0 = *(const float4*)&Crow[e0];
    const float4 c1 = *(const float4*)&Crow[e0 + 4];
    acc[0] = c0.x; acc[1] = c0.y; acc[2] = c0.z; acc[3] = c0.w;
    acc[4] = c1.x; acc[5] = c1.y; acc[6] = c1.z; acc[7] = c1.w;
#pragma unroll 4
    for (int d4 = 0; d4 < 64; ++d4) {
      const float4 cv = *(const float4*)&carry[buf][r][d4 << 2];
      const float* ap = AT + ((size_t)(d4 << 2)) * 256 + e0;
      float4 a0, a1;
      a0 = *(const float4*)(ap);           a1 = *(const float4*)(ap + 4);
      acc[0] += a0.x * cv.x; acc[1] += a0.y * cv.x; acc[2] += a0.z * cv.x; acc[3] += a0.w * cv.x;
      acc[4] += a1.x * cv.x; acc[5] += a1.y * cv.x; acc[6] += a1.z * cv.x; acc[7] += a1.w * cv.x;
      a0 = *(const float4*)(ap + 256);     a1 = *(const float4*)(ap + 260);
      acc[0] += a0.x * cv.y; acc[1] += a0.y * cv.y; acc[2] += a0.z * cv.y; acc[3] += a0.w * cv.y;
      acc[4] += a1.x * cv.y; acc[5] += a1.y * cv.y; acc[6] += a1.z * cv.y; acc[7] += a1.w * cv.y;
      a0 = *(const float4*)(ap + 512);     a1 = *(const float4*)(ap + 516);
      acc[0] += a0.x * cv.z; acc[1] += a0.y * cv.z; acc[2] += a0.z * cv.z; acc[3] += a0.w * cv.z;
      acc[4] += a1.x * cv.z; acc[5] += a1.y * cv.z; acc[6] += a1.z * cv.z; acc[7] += a1.w * cv.z;
      a0 = *(const float4*)(ap + 768);     a1 = *(const float4*)(ap + 772);
      acc[0] += a0.x * cv.w; acc[1] += a0.y * cv.w; acc[2] += a0.z * cv.w; acc[3] += a0.w * cv.w;
      acc[4] += a1.x * cv.w; acc[5] += a1.y * cv.w; acc[6] += a1.z * cv.w; acc[7] += a1.w * cv.w;
    }
    buf ^= 1;
    *(float4*)&carry[buf][r][e0]     = make_float4(acc[0], acc[1], acc[2], acc[3]);
    *(float4*)&carry[buf][r][e0 + 4] = make_float4(acc[4], acc[5], acc[6], acc[7]);
    if (w1out) {
      *(float4*)&Wrow[e0] =
          make_float4(ileakyf(acc[0]), ileakyf(acc[1]), ileakyf(acc[2]), ileakyf(acc[3]));
      *(float4*)&Wrow[e0 + 4] =
          make_float4(ileakyf(acc[4]), ileakyf(acc[5]), ileakyf(acc[6]), ileakyf(acc[7]));
      Wrow += 256;
    }
    __syncthreads();
    Crow += 256;
  }

  if (Lend) {
    *(float4*)&Lend[(size_t)(rho0 + r) * 256 + e0]     = make_float4(acc[0], acc[1], acc[2], acc[3]);
    *(float4*)&Lend[(size_t)(rho0 + r) * 256 + e0 + 4] = make_float4(acc[4], acc[5], acc[6], acc[7]);
  }
}

// ---------------------------------------------------------------------------
// Boundary recurrence over chunk boundaries: E[k+1] = P*E[k] + Lend[k],
// E[0] = z0, P = A^CHL (passed transposed: PT[d][e] = P[e][d]).
// grid = 32 (batch), block = 256 (e). Stores entry carries E[k] for phase 3.
// ---------------------------------------------------------------------------
__global__ __launch_bounds__(256) void boundary_kernel(
    const float* __restrict__ PT, const float* __restrict__ z0,
    const float* __restrict__ Lend, float* __restrict__ Earr) {
  const int b = blockIdx.x, e = threadIdx.x;
  __shared__ float Ec[256];
  Ec[e] = z0[(size_t)b * 256 + e];
  __syncthreads();
  for (int k = 0; k < NCH; ++k) {
    Earr[((size_t)k * BSZ + b) * 256 + e] = Ec[e];
    float acc = Lend[((size_t)k * BSZ + b) * 256 + e];
#pragma unroll 4
    for (int d4 = 0; d4 < 64; ++d4) {
      const float4 ev = *(const float4*)&Ec[d4 * 4];
      acc += PT[(size_t)(4 * d4 + 0) * 256 + e] * ev.x +
             PT[(size_t)(4 * d4 + 1) * 256 + e] * ev.y +
             PT[(size_t)(4 * d4 + 2) * 256 + e] * ev.z +
             PT[(size_t)(4 * d4 + 3) * 256 + e] * ev.w;
    }
    __syncthreads();
    Ec[e] = acc;
    __syncthreads();
  }
}

// ---------------------------------------------------------------------------
extern "C" void kernel_launch(void* const* d_in, const int* in_sizes, int n_in,
                              void* d_out, int out_size, void* d_ws, size_t ws_size,
                              hipStream_t stream) {
  const float* in  = (const float*)d_in[0];
  const float* We1 = (const float*)d_in[1];
  const float* be1 = (const float*)d_in[2];
  const float* We2 = (const float*)d_in[3];
  const float* be2 = (const float*)d_in[4];
  const float* A_W = (const float*)d_in[5];
  const float* A_b = (const float*)d_in[6];
  const float* B_W = (const float*)d_in[7];
  const float* B_b = (const float*)d_in[8];
  const float* Wd1 = (const float*)d_in[9];
  const float* bd1 = (const float*)d_in[10];
  const float* Wd2 = (const float*)d_in[11];
  const float* bd2 = (const float*)d_in[12];
  float* out = (float*)d_out;

  float* ws   = (float*)d_ws;
  float* Cbuf = ws;                    // 16,777,216 floats (c_t = Bu + B_b + A_b)
  float* AT   = Cbuf + 16777216;       // 65,536
  float* PT   = AT + 65536;            // 65,536
  float* Pa   = PT + 65536;            // 65,536
  float* Pb   = Pa + 65536;            // 65,536
  float* Pc   = Pb + 65536;            // 65,536
  float* z0   = Pc + 65536;            // 8,192
  float* Lend = z0 + 8192;             // 524,288
  float* Earr = Lend + 524288;         // 524,288  (total ~72.7 MB)

  const dim3 tblk(32, 8), tgrid(8, 8);
  const dim3 gblk(256);

  // A^T (phase kernels need AT[d][e])
  transpose256<<<tgrid, tblk, 0, stream>>>(A_W, AT);
  // encoder (t = 0 only)
  encoder_kernel<<<32, 256, 0, stream>>>(in, We1, be1, We2, be2, z0);
  // c_t = u_t @ B_W^T + B_b + A_b   (u strided inside padded_input)
  gemm_tn<<<dim3(512, 2), gblk, 0, stream>>>(in, INDIM, D256, B_W, ALEN, A_b, B_b, 0, Cbuf);

  // P = A^32 by repeated squaring (gemm_tn computes X @ Y when given Y^T)
  gemm_tn<<<dim3(2, 2), gblk, 0, stream>>>(A_W, 256, 0, AT, 256, nullptr, nullptr, 0, Pa);  // A^2
  transpose256<<<tgrid, tblk, 0, stream>>>(Pa, Pb);
  gemm_tn<<<dim3(2, 2), gblk, 0, stream>>>(Pa, 256, 0, Pb, 256, nullptr, nullptr, 0, Pc);   // A^4
  transpose256<<<tgrid, tblk, 0, stream>>>(Pc, Pa);
  gemm_tn<<<dim3(2, 2), gblk, 0, stream>>>(Pc, 256, 0, Pa, 256, nullptr, nullptr, 0, Pb);   // A^8
  transpose256<<<tgrid, tblk, 0, stream>>>(Pb, Pc);
  gemm_tn<<<dim3(2, 2), gblk, 0, stream>>>(Pb, 256, 0, Pc, 256, nullptr, nullptr, 0, Pa);   // A^16
  transpose256<<<tgrid, tblk, 0, stream>>>(Pa, Pb);
  gemm_tn<<<dim3(2, 2), gblk, 0, stream>>>(Pa, 256, 0, Pb, 256, nullptr, nullptr, 0, Pc);   // A^32
  transpose256<<<tgrid, tblk, 0, stream>>>(Pc, PT);

  // phase 1: local chunk scans (zero init) -> Lend
  phase_kernel<<<256, gblk, 0, stream>>>(AT, Cbuf, nullptr, Lend, nullptr);
  // boundary: propagate carries across chunks -> Earr
  boundary_kernel<<<32, 256, 0, stream>>>(PT, z0, Lend, Earr);
  // phase 3: true scans, emit w1 = inv_leaky(z1) into d_out (scratch use)
  phase_kernel<<<256, gblk, 0, stream>>>(AT, Cbuf, Earr, nullptr, out);
  // decoder 1: w2 = inv_leaky(w1 @ Wd1^T + bd1) -> Cbuf (reuse)
  gemm_tn<<<dim3(512, 2), gblk, 0, stream>>>(out, 256, 0, Wd1, 256, bd1, nullptr, 2, Cbuf);
  // decoder 2: y = w2 @ Wd2^T + bd2 -> d_out
  gemm_tn<<<dim3(512, 2), gblk, 0, stream>>>(Cbuf, 256, 0, Wd2, 256, bd2, nullptr, 0, out);
}

// Round 3
// 1605.882 us; speedup vs baseline: 2.6004x; 2.6004x over previous
//
#include <hip/hip_runtime.h>

#define D256 256
#define ALEN 128
#define INDIM 512
#define BSZ 32
#define TLEN 2048
#define CHL 32     // chunk length
#define NCH 64     // number of chunks

typedef __attribute__((ext_vector_type(8))) short short8;  // 8 x bf16
typedef __attribute__((ext_vector_type(4))) float f32x4;

__device__ __forceinline__ float leakyf(float x)  { return x < 0.f ? 0.01f * x : x; }
__device__ __forceinline__ float ileakyf(float x) { return x < 0.f ? x * 100.0f : x; }

__device__ __forceinline__ unsigned short f2bf(float f) {
  unsigned int x = __float_as_uint(f);
  unsigned int r = x + 0x7FFFu + ((x >> 16) & 1u);  // RNE
  return (unsigned short)(r >> 16);
}

__device__ __forceinline__ void gload16(const void* g, const void* l) {
  __builtin_amdgcn_global_load_lds(
      (const __attribute__((address_space(1))) unsigned int*)g,
      (__attribute__((address_space(3))) unsigned int*)l, 16, 0, 0);
}

// ---------------------------------------------------------------------------
// bf16 MFMA GEMM: Out[m][n] = sum_k In[m][k]*W[n][k] (+bias1[n]+bias2[n], act)
// N = 256 global (Out row stride 256). 128x128 tile, BK=32, 4 waves, each wave
// 64x64 via 4x4 of 16x16x32 MFMA. global_load_lds width=16 staging (m97).
// out_bf16: store ushort bf16; ileaky_act applied after bias.
// ---------------------------------------------------------------------------
__global__ __launch_bounds__(256) void gemm_mfma(
    const unsigned short* __restrict__ In, int K,
    const unsigned short* __restrict__ W,
    const float* __restrict__ bias1, const float* __restrict__ bias2,
    int ileaky_act, int out_bf16, void* __restrict__ Outp) {
  __shared__ char lds[16384];  // A tile 8KB @0, B tile 8KB @8192
  const int tid = threadIdx.x;
  const int lane = tid & 63, w = tid >> 6;
  const int m0 = blockIdx.x * 128, n0 = blockIdx.y * 128;
  const int wm = (w & 1) * 64, wn = (w >> 1) * 64;
  const int quad = lane >> 4, l16 = lane & 15;

  f32x4 acc[4][4];
#pragma unroll
  for (int i = 0; i < 4; ++i)
#pragma unroll
    for (int j = 0; j < 4; ++j) acc[i][j] = {0.f, 0.f, 0.f, 0.f};

  for (int kb = 0; kb < K; kb += 32) {
    __syncthreads();  // previous tile's reads done before overwrite
#pragma unroll
    for (int q = 0; q < 2; ++q) {
      // chunk-slot id: 512 chunks of 16B per tile; lane-sequential LDS dest
      const int id = (w * 2 + q) * 64 + lane;
      const int row = id >> 2, ch = id & 3;
      gload16(In + (size_t)(m0 + row) * K + kb + ch * 8,
              lds + (w * 2 + q) * 1024);
      gload16(W + (size_t)(n0 + row) * K + kb + ch * 8,
              lds + 8192 + (w * 2 + q) * 1024);
    }
    __syncthreads();  // vmcnt(0) drain: staging visible

    short8 af[4], bf[4];
#pragma unroll
    for (int i = 0; i < 4; ++i) {
      af[i] = *(const short8*)(lds + ((wm + i * 16 + l16) * 64 + quad * 16));
      bf[i] = *(const short8*)(lds + 8192 + ((wn + i * 16 + l16) * 64 + quad * 16));
    }
#pragma unroll
    for (int i = 0; i < 4; ++i)
#pragma unroll
      for (int j = 0; j < 4; ++j)
        acc[i][j] = __builtin_amdgcn_mfma_f32_16x16x32_bf16(af[i], bf[j], acc[i][j], 0, 0, 0);
  }

  // epilogue: C/D layout col=lane&15, row=quad*4+reg [m89]
#pragma unroll
  for (int j = 0; j < 4; ++j) {
    const int n = n0 + wn + j * 16 + l16;
    const float bv = (bias1 ? bias1[n] : 0.f) + (bias2 ? bias2[n] : 0.f);
#pragma unroll
    for (int i = 0; i < 4; ++i) {
#pragma unroll
      for (int r = 0; r < 4; ++r) {
        const int m = m0 + wm + i * 16 + quad * 4 + r;
        float v = acc[i][j][r] + bv;
        if (ileaky_act) v = ileakyf(v);
        if (out_bf16)
          ((unsigned short*)Outp)[(size_t)m * 256 + n] = f2bf(v);
        else
          ((float*)Outp)[(size_t)m * 256 + n] = v;
      }
    }
  }
}

// ---------------------------------------------------------------------------
// Small fp32 GEMM for the A-power chain (precision-critical, fp32 only).
// 256x256x256: Out[m][n] = sum_k In[m][k]*W[n][k]. 64x64 tile, 4x4 micro,
// ~80 VGPR -> no spills (R1 post-mortem: 8x8 micro spilled at 256 VGPR).
// ---------------------------------------------------------------------------
__global__ __launch_bounds__(256) void gemm_small(
    const float* __restrict__ In, const float* __restrict__ W,
    float* __restrict__ Out) {
  __shared__ float a_lds[64][40];
  __shared__ float b_lds[64][40];
  const int tid = threadIdx.x;
  const int tm = tid >> 4, tn = tid & 15;
  const int m0 = blockIdx.x * 64, n0 = blockIdx.y * 64;
  float acc[4][4];
#pragma unroll
  for (int i = 0; i < 4; ++i)
#pragma unroll
    for (int j = 0; j < 4; ++j) acc[i][j] = 0.f;

  for (int kb = 0; kb < 256; kb += 32) {
    __syncthreads();
#pragma unroll
    for (int q = 0; q < 2; ++q) {
      const int slot = q * 256 + tid;  // 512 float4 slots per tile
      const int row = slot >> 3, s4 = slot & 7;
      *(float4*)&a_lds[row][s4 * 4] = *(const float4*)&In[(size_t)(m0 + row) * 256 + kb + s4 * 4];
      *(float4*)&b_lds[row][s4 * 4] = *(const float4*)&W[(size_t)(n0 + row) * 256 + kb + s4 * 4];
    }
    __syncthreads();
#pragma unroll
    for (int k4 = 0; k4 < 8; ++k4) {
      float4 a4[4], b4[4];
#pragma unroll
      for (int i = 0; i < 4; ++i) a4[i] = *(const float4*)&a_lds[tm * 4 + i][k4 * 4];
#pragma unroll
      for (int j = 0; j < 4; ++j) b4[j] = *(const float4*)&b_lds[tn * 4 + j][k4 * 4];
#pragma unroll
      for (int i = 0; i < 4; ++i)
#pragma unroll
        for (int j = 0; j < 4; ++j)
          acc[i][j] += a4[i].x * b4[j].x + a4[i].y * b4[j].y +
                       a4[i].z * b4[j].z + a4[i].w * b4[j].w;
    }
  }
#pragma unroll
  for (int i = 0; i < 4; ++i) {
    const int m = m0 + tm * 4 + i;
    *(float4*)&Out[(size_t)m * 256 + n0 + tn * 4] =
        make_float4(acc[i][0], acc[i][1], acc[i][2], acc[i][3]);
  }
}

// ---------------------------------------------------------------------------
// 256x256 transpose (out[d][e] = in[e][d])
// ---------------------------------------------------------------------------
__global__ __launch_bounds__(256) void transpose256(const float* __restrict__ in,
                                                    float* __restrict__ out) {
  __shared__ float t[32][33];
  const int lx = threadIdx.x, ly = threadIdx.y;
  const int bx = blockIdx.x * 32, by = blockIdx.y * 32;
#pragma unroll
  for (int i = 0; i < 4; ++i)
    t[ly + 8 * i][lx] = in[(size_t)(by + ly + 8 * i) * 256 + bx + lx];
  __syncthreads();
#pragma unroll
  for (int i = 0; i < 4; ++i)
    out[(size_t)(bx + ly + 8 * i) * 256 + by + lx] = t[lx][ly + 8 * i];
}

// ---------------------------------------------------------------------------
// Encoder, t=0 only (z[:,0,:] is all that survives into the scan)
// ---------------------------------------------------------------------------
__global__ __launch_bounds__(256) void encoder_kernel(
    const float* __restrict__ in, const float* __restrict__ We1,
    const float* __restrict__ be1, const float* __restrict__ We2,
    const float* __restrict__ be2, float* __restrict__ z0) {
  const int b = blockIdx.x, e = threadIdx.x;
  __shared__ float xb[256];
  __shared__ float h1[256];
  xb[e] = in[(size_t)b * TLEN * INDIM + e];
  __syncthreads();
  float acc = be1[e];
  const float4* w = (const float4*)(We1 + (size_t)e * 256);
#pragma unroll 8
  for (int d4 = 0; d4 < 64; ++d4) {
    float4 wv = w[d4];
    acc += wv.x * xb[4 * d4] + wv.y * xb[4 * d4 + 1] + wv.z * xb[4 * d4 + 2] + wv.w * xb[4 * d4 + 3];
  }
  h1[e] = leakyf(acc);
  __syncthreads();
  float a2 = be2[e];
  w = (const float4*)(We2 + (size_t)e * 256);
#pragma unroll 8
  for (int d4 = 0; d4 < 64; ++d4) {
    float4 wv = w[d4];
    a2 += wv.x * h1[4 * d4] + wv.y * h1[4 * d4 + 1] + wv.z * h1[4 * d4 + 2] + wv.w * h1[4 * d4 + 3];
  }
  z0[(size_t)b * 256 + e] = leakyf(a2);
}

// ---------------------------------------------------------------------------
// extract u columns (fp32, strided) -> dense bf16 [65536][128]
// grid MUST cover 65536 rows x 32 float4 = 2,097,152 threads -> 8192 blocks.
// (R2 bug: 2048 blocks covered only 1/4 of rows -> absmax 6338.)
// ---------------------------------------------------------------------------
__global__ __launch_bounds__(256) void extract_u(const float* __restrict__ in,
                                                 unsigned short* __restrict__ ubuf) {
  const int gid = blockIdx.x * 256 + threadIdx.x;
  const int row = gid >> 5;
  const int c = (gid & 31) * 4;
  float4 v = *(const float4*)&in[(size_t)row * INDIM + 256 + c];
  *(ushort4*)&ubuf[(size_t)row * 128 + c] =
      make_ushort4(f2bf(v.x), f2bf(v.y), f2bf(v.z), f2bf(v.w));
}

// fp32 -> bf16 (weights); n multiple of 1024
__global__ __launch_bounds__(256) void f2bf_kernel(const float* __restrict__ in,
                                                   unsigned short* __restrict__ out, int n) {
  const int i4 = blockIdx.x * 256 + threadIdx.x;
  if (i4 * 4 < n) {
    float4 v = *(const float4*)&in[(size_t)i4 * 4];
    *(ushort4*)&out[(size_t)i4 * 4] = make_ushort4(f2bf(v.x), f2bf(v.y), f2bf(v.z), f2bf(v.w));
  }
}

// ---------------------------------------------------------------------------
// Chunked-scan phase kernel (fp32 for precision). Phase1: Einit=null, write
// Lend. Phase3: Einit=Earr, write w1 = bf16(inv_leaky(s_t)) each step.
// ---------------------------------------------------------------------------
__global__ __launch_bounds__(256) void phase_kernel(
    const float* __restrict__ AT, const float* __restrict__ Cbuf,
    const float* __restrict__ Einit, float* __restrict__ Lend,
    unsigned short* __restrict__ w1out) {
  const int tid = threadIdx.x;
  const int r = tid >> 5, cg = tid & 31, e0 = cg << 3;
  const int rho0 = blockIdx.x << 3;
  const int k = rho0 >> 5;
  const int b = (rho0 & 31) + r;
  __shared__ float carry[2][8][268];

  if (Einit) {
    *(float4*)&carry[0][r][e0]     = *(const float4*)&Einit[(size_t)(rho0 + r) * 256 + e0];
    *(float4*)&carry[0][r][e0 + 4] = *(const float4*)&Einit[(size_t)(rho0 + r) * 256 + e0 + 4];
  } else {
    *(float4*)&carry[0][r][e0]     = make_float4(0.f, 0.f, 0.f, 0.f);
    *(float4*)&carry[0][r][e0 + 4] = make_float4(0.f, 0.f, 0.f, 0.f);
  }
  __syncthreads();

  int buf = 0;
  const float* Crow = Cbuf + ((size_t)b * TLEN + (size_t)k * CHL) * 256;
  unsigned short* Wrow = w1out ? w1out + ((size_t)b * TLEN + (size_t)k * CHL) * 256 : (unsigned short*)0;
  float acc[8];

  for (int j = 0; j < CHL; ++j) {
    const float4 c0 = *(const float4*)&Crow[e0];
    const float4 c1 = *(const float4*)&Crow[e0 + 4];
    acc[0] = c0.x; acc[1] = c0.y; acc[2] = c0.z; acc[3] = c0.w;
    acc[4] = c1.x; acc[5] = c1.y; acc[6] = c1.z; acc[7] = c1.w;
#pragma unroll 4
    for (int d4 = 0; d4 < 64; ++d4) {
      const float4 cv = *(const float4*)&carry[buf][r][d4 << 2];
      const float* ap = AT + ((size_t)(d4 << 2)) * 256 + e0;
      float4 a0, a1;
      a0 = *(const float4*)(ap);           a1 = *(const float4*)(ap + 4);
      acc[0] += a0.x * cv.x; acc[1] += a0.y * cv.x; acc[2] += a0.z * cv.x; acc[3] += a0.w * cv.x;
      acc[4] += a1.x * cv.x; acc[5] += a1.y * cv.x; acc[6] += a1.z * cv.x; acc[7] += a1.w * cv.x;
      a0 = *(const float4*)(ap + 256);     a1 = *(const float4*)(ap + 260);
      acc[0] += a0.x * cv.y; acc[1] += a0.y * cv.y; acc[2] += a0.z * cv.y; acc[3] += a0.w * cv.y;
      acc[4] += a1.x * cv.y; acc[5] += a1.y * cv.y; acc[6] += a1.z * cv.y; acc[7] += a1.w * cv.y;
      a0 = *(const float4*)(ap + 512);     a1 = *(const float4*)(ap + 516);
      acc[0] += a0.x * cv.z; acc[1] += a0.y * cv.z; acc[2] += a0.z * cv.z; acc[3] += a0.w * cv.z;
      acc[4] += a1.x * cv.z; acc[5] += a1.y * cv.z; acc[6] += a1.z * cv.z; acc[7] += a1.w * cv.z;
      a0 = *(const float4*)(ap + 768);     a1 = *(const float4*)(ap + 772);
      acc[0] += a0.x * cv.w; acc[1] += a0.y * cv.w; acc[2] += a0.z * cv.w; acc[3] += a0.w * cv.w;
      acc[4] += a1.x * cv.w; acc[5] += a1.y * cv.w; acc[6] += a1.z * cv.w; acc[7] += a1.w * cv.w;
    }
    buf ^= 1;
    *(float4*)&carry[buf][r][e0]     = make_float4(acc[0], acc[1], acc[2], acc[3]);
    *(float4*)&carry[buf][r][e0 + 4] = make_float4(acc[4], acc[5], acc[6], acc[7]);
    if (w1out) {
      const unsigned int p0 = (unsigned int)f2bf(ileakyf(acc[0])) | ((unsigned int)f2bf(ileakyf(acc[1])) << 16);
      const unsigned int p1 = (unsigned int)f2bf(ileakyf(acc[2])) | ((unsigned int)f2bf(ileakyf(acc[3])) << 16);
      const unsigned int p2 = (unsigned int)f2bf(ileakyf(acc[4])) | ((unsigned int)f2bf(ileakyf(acc[5])) << 16);
      const unsigned int p3 = (unsigned int)f2bf(ileakyf(acc[6])) | ((unsigned int)f2bf(ileakyf(acc[7])) << 16);
      *(uint4*)&Wrow[e0] = make_uint4(p0, p1, p2, p3);
      Wrow += 256;
    }
    __syncthreads();
    Crow += 256;
  }

  if (Lend) {
    *(float4*)&Lend[(size_t)(rho0 + r) * 256 + e0]     = make_float4(acc[0], acc[1], acc[2], acc[3]);
    *(float4*)&Lend[(size_t)(rho0 + r) * 256 + e0 + 4] = make_float4(acc[4], acc[5], acc[6], acc[7]);
  }
}

// ---------------------------------------------------------------------------
// Boundary recurrence: E[k+1] = P*E[k] + Lend[k], E[0]=z0, P=A^32 (PT = P^T)
// ---------------------------------------------------------------------------
__global__ __launch_bounds__(256) void boundary_kernel(
    const float* __restrict__ PT, const float* __restrict__ z0,
    const float* __restrict__ Lend, float* __restrict__ Earr) {
  const int b = blockIdx.x, e = threadIdx.x;
  __shared__ float Ec[256];
  Ec[e] = z0[(size_t)b * 256 + e];
  __syncthreads();
  for (int k = 0; k < NCH; ++k) {
    Earr[((size_t)k * BSZ + b) * 256 + e] = Ec[e];
    float acc = Lend[((size_t)k * BSZ + b) * 256 + e];
#pragma unroll 4
    for (int d4 = 0; d4 < 64; ++d4) {
      const float4 ev = *(const float4*)&Ec[d4 * 4];
      acc += PT[(size_t)(4 * d4 + 0) * 256 + e] * ev.x +
             PT[(size_t)(4 * d4 + 1) * 256 + e] * ev.y +
             PT[(size_t)(4 * d4 + 2) * 256 + e] * ev.z +
             PT[(size_t)(4 * d4 + 3) * 256 + e] * ev.w;
    }
    __syncthreads();
    Ec[e] = acc;
    __syncthreads();
  }
}

// ---------------------------------------------------------------------------
extern "C" void kernel_launch(void* const* d_in, const int* in_sizes, int n_in,
                              void* d_out, int out_size, void* d_ws, size_t ws_size,
                              hipStream_t stream) {
  const float* in  = (const float*)d_in[0];
  const float* We1 = (const float*)d_in[1];
  const float* be1 = (const float*)d_in[2];
  const float* We2 = (const float*)d_in[3];
  const float* be2 = (const float*)d_in[4];
  const float* A_W = (const float*)d_in[5];
  const float* A_b = (const float*)d_in[6];
  const float* B_W = (const float*)d_in[7];
  const float* B_b = (const float*)d_in[8];
  const float* Wd1 = (const float*)d_in[9];
  const float* bd1 = (const float*)d_in[10];
  const float* Wd2 = (const float*)d_in[11];
  const float* bd2 = (const float*)d_in[12];
  float* out = (float*)d_out;

  // workspace (fp32 units), total ~73.0 MB
  float* ws   = (float*)d_ws;
  float* Cbuf = ws;                    // 16,777,216 f  (c_t fp32; later reused: w2 bf16)
  float* AT   = Cbuf + 16777216;       // 65,536
  float* PT   = AT + 65536;            // 65,536
  float* Pa   = PT + 65536;            // 65,536
  float* Pb   = Pa + 65536;            // 65,536
  float* Pc   = Pb + 65536;            // 65,536
  float* z0   = Pc + 65536;            // 8,192
  float* Lend = z0 + 8192;             // 524,288
  float* Earr = Lend + 524288;         // 524,288
  unsigned short* BWb  = (unsigned short*)(Earr + 524288);  // 32,768 us
  unsigned short* Wd1b = BWb + 32768;                       // 65,536 us
  unsigned short* Wd2b = Wd1b + 65536;                      // 65,536 us

  // d_out staging: [0,16MB) ubuf bf16; [16MB,48MB) w1 bf16; final fp32 overwrites all
  unsigned short* ubuf = (unsigned short*)d_out;            // 65536x128 bf16
  unsigned short* w1   = ubuf + 8388608;                    // 65536x256 bf16
  unsigned short* w2   = (unsigned short*)Cbuf;             // 65536x256 bf16 (Cbuf dead after phase3)

  const dim3 tblk(32, 8), tgrid(8, 8);

  transpose256<<<tgrid, tblk, 0, stream>>>(A_W, AT);
  encoder_kernel<<<32, 256, 0, stream>>>(in, We1, be1, We2, be2, z0);
  extract_u<<<8192, 256, 0, stream>>>(in, ubuf);
  f2bf_kernel<<<32, 256, 0, stream>>>(B_W, BWb, 32768);
  f2bf_kernel<<<64, 256, 0, stream>>>(Wd1, Wd1b, 65536);
  f2bf_kernel<<<64, 256, 0, stream>>>(Wd2, Wd2b, 65536);

  // c_t = u @ B_W^T + B_b + A_b -> Cbuf (fp32 out)
  gemm_mfma<<<dim3(512, 2), 256, 0, stream>>>(ubuf, ALEN, BWb, A_b, B_b, 0, 0, Cbuf);

  // P = A^32 by repeated squaring (fp32; precision-critical)
  gemm_small<<<dim3(4, 4), 256, 0, stream>>>(A_W, AT, Pa);   // A^2
  transpose256<<<tgrid, tblk, 0, stream>>>(Pa, Pb);
  gemm_small<<<dim3(4, 4), 256, 0, stream>>>(Pa, Pb, Pc);    // A^4
  transpose256<<<tgrid, tblk, 0, stream>>>(Pc, Pa);
  gemm_small<<<dim3(4, 4), 256, 0, stream>>>(Pc, Pa, Pb);    // A^8
  transpose256<<<tgrid, tblk, 0, stream>>>(Pb, Pc);
  gemm_small<<<dim3(4, 4), 256, 0, stream>>>(Pb, Pc, Pa);    // A^16
  transpose256<<<tgrid, tblk, 0, stream>>>(Pa, Pb);
  gemm_small<<<dim3(4, 4), 256, 0, stream>>>(Pa, Pb, Pc);    // A^32
  transpose256<<<tgrid, tblk, 0, stream>>>(Pc, PT);

  phase_kernel<<<256, 256, 0, stream>>>(AT, Cbuf, nullptr, Lend, nullptr);
  boundary_kernel<<<32, 256, 0, stream>>>(PT, z0, Lend, Earr);
  phase_kernel<<<256, 256, 0, stream>>>(AT, Cbuf, Earr, nullptr, w1);

  // dec1: w2 = bf16(inv_leaky(w1 @ Wd1^T + bd1)) -> Cbuf region
  gemm_mfma<<<dim3(512, 2), 256, 0, stream>>>(w1, D256, Wd1b, bd1, nullptr, 1, 1, w2);
  // dec2: y = w2 @ Wd2^T + bd2 -> d_out (fp32)
  gemm_mfma<<<dim3(512, 2), 256, 0, stream>>>(w2, D256, Wd2b, bd2, nullptr, 0, 0, out);
}

// Round 4
// 1507.018 us; speedup vs baseline: 2.7710x; 1.0656x over previous
//
#include <hip/hip_runtime.h>

#define D256 256
#define ALEN 128
#define INDIM 512
#define BSZ 32
#define TLEN 2048
#define CHL 32     // chunk length
#define NCH 64     // number of chunks

typedef __attribute__((ext_vector_type(8))) short short8;  // 8 x bf16
typedef __attribute__((ext_vector_type(4))) float f32x4;

__device__ __forceinline__ float leakyf(float x)  { return x < 0.f ? 0.01f * x : x; }
__device__ __forceinline__ float ileakyf(float x) { return x < 0.f ? x * 100.0f : x; }

__device__ __forceinline__ unsigned short f2bf(float f) {
  unsigned int x = __float_as_uint(f);
  unsigned int r = x + 0x7FFFu + ((x >> 16) & 1u);  // RNE
  return (unsigned short)(r >> 16);
}

__device__ __forceinline__ void gload16(const void* g, const void* l) {
  __builtin_amdgcn_global_load_lds(
      (const __attribute__((address_space(1))) unsigned int*)g,
      (__attribute__((address_space(3))) unsigned int*)l, 16, 0, 0);
}

// ---------------------------------------------------------------------------
// bf16 MFMA GEMM (m97 structure): Out[m][n] = sum_k In[m][k]*W[n][k]
// (+bias1[n]+bias2[n], optional inv_leaky). 128x128 tile, BK=32, 4 waves.
// ---------------------------------------------------------------------------
__global__ __launch_bounds__(256) void gemm_mfma(
    const unsigned short* __restrict__ In, int K,
    const unsigned short* __restrict__ W,
    const float* __restrict__ bias1, const float* __restrict__ bias2,
    int ileaky_act, int out_bf16, void* __restrict__ Outp) {
  __shared__ char lds[16384];  // A tile 8KB @0, B tile 8KB @8192
  const int tid = threadIdx.x;
  const int lane = tid & 63, w = tid >> 6;
  const int m0 = blockIdx.x * 128, n0 = blockIdx.y * 128;
  const int wm = (w & 1) * 64, wn = (w >> 1) * 64;
  const int quad = lane >> 4, l16 = lane & 15;

  f32x4 acc[4][4];
#pragma unroll
  for (int i = 0; i < 4; ++i)
#pragma unroll
    for (int j = 0; j < 4; ++j) acc[i][j] = {0.f, 0.f, 0.f, 0.f};

  for (int kb = 0; kb < K; kb += 32) {
    __syncthreads();
#pragma unroll
    for (int q = 0; q < 2; ++q) {
      const int id = (w * 2 + q) * 64 + lane;
      const int row = id >> 2, ch = id & 3;
      gload16(In + (size_t)(m0 + row) * K + kb + ch * 8,
              lds + (w * 2 + q) * 1024);
      gload16(W + (size_t)(n0 + row) * K + kb + ch * 8,
              lds + 8192 + (w * 2 + q) * 1024);
    }
    __syncthreads();

    short8 af[4], bf[4];
#pragma unroll
    for (int i = 0; i < 4; ++i) {
      af[i] = *(const short8*)(lds + ((wm + i * 16 + l16) * 64 + quad * 16));
      bf[i] = *(const short8*)(lds + 8192 + ((wn + i * 16 + l16) * 64 + quad * 16));
    }
#pragma unroll
    for (int i = 0; i < 4; ++i)
#pragma unroll
      for (int j = 0; j < 4; ++j)
        acc[i][j] = __builtin_amdgcn_mfma_f32_16x16x32_bf16(af[i], bf[j], acc[i][j], 0, 0, 0);
  }

#pragma unroll
  for (int j = 0; j < 4; ++j) {
    const int n = n0 + wn + j * 16 + l16;
    const float bv = (bias1 ? bias1[n] : 0.f) + (bias2 ? bias2[n] : 0.f);
#pragma unroll
    for (int i = 0; i < 4; ++i) {
#pragma unroll
      for (int r = 0; r < 4; ++r) {
        const int m = m0 + wm + i * 16 + quad * 4 + r;
        float v = acc[i][j][r] + bv;
        if (ileaky_act) v = ileakyf(v);
        if (out_bf16)
          ((unsigned short*)Outp)[(size_t)m * 256 + n] = f2bf(v);
        else
          ((float*)Outp)[(size_t)m * 256 + n] = v;
      }
    }
  }
}

// ---------------------------------------------------------------------------
// fp32 squaring GEMM for A-power chain: given (X, X^T) emit (X^2, (X^2)^T).
// Out[m][n] = sum_k X[m][k] * XT[n][k]  = X@X.  64x64 tile, 4x4 micro.
// Dual store kills the 6 transpose launches of R3's chain.
// ---------------------------------------------------------------------------
__global__ __launch_bounds__(256) void gemm_sq(
    const float* __restrict__ X, const float* __restrict__ XT,
    float* __restrict__ Out, float* __restrict__ OutT) {
  __shared__ float a_lds[64][40];
  __shared__ float b_lds[64][40];
  const int tid = threadIdx.x;
  const int tm = tid >> 4, tn = tid & 15;
  const int m0 = blockIdx.x * 64, n0 = blockIdx.y * 64;
  float acc[4][4];
#pragma unroll
  for (int i = 0; i < 4; ++i)
#pragma unroll
    for (int j = 0; j < 4; ++j) acc[i][j] = 0.f;

  for (int kb = 0; kb < 256; kb += 32) {
    __syncthreads();
#pragma unroll
    for (int q = 0; q < 2; ++q) {
      const int slot = q * 256 + tid;
      const int row = slot >> 3, s4 = slot & 7;
      *(float4*)&a_lds[row][s4 * 4] = *(const float4*)&X[(size_t)(m0 + row) * 256 + kb + s4 * 4];
      *(float4*)&b_lds[row][s4 * 4] = *(const float4*)&XT[(size_t)(n0 + row) * 256 + kb + s4 * 4];
    }
    __syncthreads();
#pragma unroll
    for (int k4 = 0; k4 < 8; ++k4) {
      float4 a4[4], b4[4];
#pragma unroll
      for (int i = 0; i < 4; ++i) a4[i] = *(const float4*)&a_lds[tm * 4 + i][k4 * 4];
#pragma unroll
      for (int j = 0; j < 4; ++j) b4[j] = *(const float4*)&b_lds[tn * 4 + j][k4 * 4];
#pragma unroll
      for (int i = 0; i < 4; ++i)
#pragma unroll
        for (int j = 0; j < 4; ++j)
          acc[i][j] += a4[i].x * b4[j].x + a4[i].y * b4[j].y +
                       a4[i].z * b4[j].z + a4[i].w * b4[j].w;
    }
  }
#pragma unroll
  for (int i = 0; i < 4; ++i) {
    const int m = m0 + tm * 4 + i;
    *(float4*)&Out[(size_t)m * 256 + n0 + tn * 4] =
        make_float4(acc[i][0], acc[i][1], acc[i][2], acc[i][3]);
#pragma unroll
    for (int j = 0; j < 4; ++j)
      OutT[(size_t)(n0 + tn * 4 + j) * 256 + m] = acc[i][j];
  }
}

// ---------------------------------------------------------------------------
// 256x256 transpose (out[d][e] = in[e][d]) — only used once now (A -> AT)
// ---------------------------------------------------------------------------
__global__ __launch_bounds__(256) void transpose256(const float* __restrict__ in,
                                                    float* __restrict__ out) {
  __shared__ float t[32][33];
  const int lx = threadIdx.x, ly = threadIdx.y;
  const int bx = blockIdx.x * 32, by = blockIdx.y * 32;
#pragma unroll
  for (int i = 0; i < 4; ++i)
    t[ly + 8 * i][lx] = in[(size_t)(by + ly + 8 * i) * 256 + bx + lx];
  __syncthreads();
#pragma unroll
  for (int i = 0; i < 4; ++i)
    out[(size_t)(bx + ly + 8 * i) * 256 + by + lx] = t[lx][ly + 8 * i];
}

// ---------------------------------------------------------------------------
// Encoder, t=0 only
// ---------------------------------------------------------------------------
__global__ __launch_bounds__(256) void encoder_kernel(
    const float* __restrict__ in, const float* __restrict__ We1,
    const float* __restrict__ be1, const float* __restrict__ We2,
    const float* __restrict__ be2, float* __restrict__ z0) {
  const int b = blockIdx.x, e = threadIdx.x;
  __shared__ float xb[256];
  __shared__ float h1[256];
  xb[e] = in[(size_t)b * TLEN * INDIM + e];
  __syncthreads();
  float acc = be1[e];
  const float4* w = (const float4*)(We1 + (size_t)e * 256);
#pragma unroll 8
  for (int d4 = 0; d4 < 64; ++d4) {
    float4 wv = w[d4];
    acc += wv.x * xb[4 * d4] + wv.y * xb[4 * d4 + 1] + wv.z * xb[4 * d4 + 2] + wv.w * xb[4 * d4 + 3];
  }
  h1[e] = leakyf(acc);
  __syncthreads();
  float a2 = be2[e];
  w = (const float4*)(We2 + (size_t)e * 256);
#pragma unroll 8
  for (int d4 = 0; d4 < 64; ++d4) {
    float4 wv = w[d4];
    a2 += wv.x * h1[4 * d4] + wv.y * h1[4 * d4 + 1] + wv.z * h1[4 * d4 + 2] + wv.w * h1[4 * d4 + 3];
  }
  z0[(size_t)b * 256 + e] = leakyf(a2);
}

// ---------------------------------------------------------------------------
// extract u columns -> dense bf16 [65536][128]; needs 8192 blocks (R2 bug).
// ---------------------------------------------------------------------------
__global__ __launch_bounds__(256) void extract_u(const float* __restrict__ in,
                                                 unsigned short* __restrict__ ubuf) {
  const int gid = blockIdx.x * 256 + threadIdx.x;
  const int row = gid >> 5;
  const int c = (gid & 31) * 4;
  float4 v = *(const float4*)&in[(size_t)row * INDIM + 256 + c];
  *(ushort4*)&ubuf[(size_t)row * 128 + c] =
      make_ushort4(f2bf(v.x), f2bf(v.y), f2bf(v.z), f2bf(v.w));
}

__global__ __launch_bounds__(256) void f2bf_kernel(const float* __restrict__ in,
                                                   unsigned short* __restrict__ out, int n) {
  const int i4 = blockIdx.x * 256 + threadIdx.x;
  if (i4 * 4 < n) {
    float4 v = *(const float4*)&in[(size_t)i4 * 4];
    *(ushort4*)&out[(size_t)i4 * 4] = make_ushort4(f2bf(v.x), f2bf(v.y), f2bf(v.z), f2bf(v.w));
  }
}

// ---------------------------------------------------------------------------
// Chunked-scan phase kernel v2 (fp32). 512 threads = 8 waves; wave w owns
// e-slice [w*32, w*32+32); lane-group r (l>>3) owns row r of the block's 8.
// Each wave reads only its A^T e-slice from L2 (256 KB/block/step total, 4x
// less than R3's 1 MB) and 2 waves/SIMD hide L2 latency (R3: 1 wave/SIMD,
// VALUBusy 16%). Arithmetic order per output identical to R3.
// ---------------------------------------------------------------------------
__global__ __launch_bounds__(512, 2) void phase_kernel(
    const float* __restrict__ AT, const float* __restrict__ Cbuf,
    const float* __restrict__ Einit, float* __restrict__ Lend,
    unsigned short* __restrict__ w1out) {
  const int tid = threadIdx.x;
  const int w = tid >> 6;
  const int l = tid & 63;
  const int r = l >> 3;
  const int le = l & 7;
  const int e0 = w * 32 + le * 4;
  const int rho0 = blockIdx.x << 3;
  const int k = rho0 >> 5;
  const int b = (rho0 & 31) + r;
  const int rho = rho0 + r;

  __shared__ float carry[2][8][260];  // 260 pad: 8 rgrp float4 reads land on distinct banks

  if (Einit) {
    *(float4*)&carry[0][r][e0] = *(const float4*)&Einit[(size_t)rho * 256 + e0];
  } else {
    *(float4*)&carry[0][r][e0] = make_float4(0.f, 0.f, 0.f, 0.f);
  }
  __syncthreads();

  const float* Abase = AT + e0;
  const float* Crow = Cbuf + ((size_t)b * TLEN + (size_t)k * CHL) * 256 + e0;
  unsigned short* Wrow =
      w1out ? w1out + ((size_t)b * TLEN + (size_t)k * CHL) * 256 + e0 : (unsigned short*)0;

  int buf = 0;
  float4 acc = make_float4(0.f, 0.f, 0.f, 0.f);
  for (int j = 0; j < CHL; ++j) {
    acc = *(const float4*)Crow;
#pragma unroll 4
    for (int d4 = 0; d4 < 64; ++d4) {
      const float4 cv = *(const float4*)&carry[buf][r][d4 * 4];
      const float* ap = Abase + (size_t)d4 * 1024;
      const float4 a0 = *(const float4*)(ap);
      const float4 a1 = *(const float4*)(ap + 256);
      const float4 a2 = *(const float4*)(ap + 512);
      const float4 a3 = *(const float4*)(ap + 768);
      acc.x += a0.x * cv.x + a1.x * cv.y + a2.x * cv.z + a3.x * cv.w;
      acc.y += a0.y * cv.x + a1.y * cv.y + a2.y * cv.z + a3.y * cv.w;
      acc.z += a0.z * cv.x + a1.z * cv.y + a2.z * cv.z + a3.z * cv.w;
      acc.w += a0.w * cv.x + a1.w * cv.y + a2.w * cv.z + a3.w * cv.w;
    }
    buf ^= 1;
    *(float4*)&carry[buf][r][e0] = acc;
    if (w1out) {
      *(ushort4*)Wrow = make_ushort4(f2bf(ileakyf(acc.x)), f2bf(ileakyf(acc.y)),
                                     f2bf(ileakyf(acc.z)), f2bf(ileakyf(acc.w)));
      Wrow += 256;
    }
    Crow += 256;
    __syncthreads();
  }
  if (Lend) *(float4*)&Lend[(size_t)rho * 256 + e0] = acc;
}

// ---------------------------------------------------------------------------
// Boundary recurrence v2: E[k+1] = P*E[k] + Lend[k]. 512 threads: wave w owns
// e-slice, lane-group r owns d-slice [r*32, r*32+32); LDS tree-reduce over r.
// ---------------------------------------------------------------------------
__global__ __launch_bounds__(512, 2) void boundary_kernel(
    const float* __restrict__ PT, const float* __restrict__ z0,
    const float* __restrict__ Lend, float* __restrict__ Earr) {
  const int tid = threadIdx.x;
  const int w = tid >> 6;
  const int l = tid & 63;
  const int r = l >> 3;
  const int le = l & 7;
  const int e0 = w * 32 + le * 4;
  const int b = blockIdx.x;
  __shared__ float Ec[256];
  __shared__ float part[8][260];

  if (tid < 256) Ec[tid] = z0[(size_t)b * 256 + tid];
  __syncthreads();

  for (int k = 0; k < NCH; ++k) {
    if (tid < 256) Earr[((size_t)k * BSZ + b) * 256 + tid] = Ec[tid];
    float4 acc = make_float4(0.f, 0.f, 0.f, 0.f);
    const float* Pbase = PT + (size_t)(r * 32) * 256 + e0;
#pragma unroll 2
    for (int d4 = 0; d4 < 8; ++d4) {
      const float4 cv = *(const float4*)&Ec[r * 32 + d4 * 4];
      const float* ap = Pbase + (size_t)d4 * 1024;
      const float4 a0 = *(const float4*)(ap);
      const float4 a1 = *(const float4*)(ap + 256);
      const float4 a2 = *(const float4*)(ap + 512);
      const float4 a3 = *(const float4*)(ap + 768);
      acc.x += a0.x * cv.x + a1.x * cv.y + a2.x * cv.z + a3.x * cv.w;
      acc.y += a0.y * cv.x + a1.y * cv.y + a2.y * cv.z + a3.y * cv.w;
      acc.z += a0.z * cv.x + a1.z * cv.y + a2.z * cv.z + a3.z * cv.w;
      acc.w += a0.w * cv.x + a1.w * cv.y + a2.w * cv.z + a3.w * cv.w;
    }
    *(float4*)&part[r][e0] = acc;
    __syncthreads();               // part complete; all Ec reads done
    float s = 0.f;
    if (tid < 256) {
      s = Lend[((size_t)k * BSZ + b) * 256 + tid];
#pragma unroll
      for (int rr = 0; rr < 8; ++rr) s += part[rr][tid];
    }
    __syncthreads();               // part reads done before next overwrite
    if (tid < 256) Ec[tid] = s;
    __syncthreads();               // new Ec visible
  }
}

// ---------------------------------------------------------------------------
extern "C" void kernel_launch(void* const* d_in, const int* in_sizes, int n_in,
                              void* d_out, int out_size, void* d_ws, size_t ws_size,
                              hipStream_t stream) {
  const float* in  = (const float*)d_in[0];
  const float* We1 = (const float*)d_in[1];
  const float* be1 = (const float*)d_in[2];
  const float* We2 = (const float*)d_in[3];
  const float* be2 = (const float*)d_in[4];
  const float* A_W = (const float*)d_in[5];
  const float* A_b = (const float*)d_in[6];
  const float* B_W = (const float*)d_in[7];
  const float* B_b = (const float*)d_in[8];
  const float* Wd1 = (const float*)d_in[9];
  const float* bd1 = (const float*)d_in[10];
  const float* Wd2 = (const float*)d_in[11];
  const float* bd2 = (const float*)d_in[12];
  float* out = (float*)d_out;

  float* ws   = (float*)d_ws;
  float* Cbuf = ws;                    // 16,777,216 f
  float* AT   = Cbuf + 16777216;       // 65,536
  float* PT   = AT + 65536;            // 65,536
  float* Pa   = PT + 65536;            // 65,536
  float* PaT  = Pa + 65536;            // 65,536
  float* Pb   = PaT + 65536;           // 65,536
  float* PbT  = Pb + 65536;            // 65,536
  float* z0   = PbT + 65536;           // 8,192
  float* Lend = z0 + 8192;             // 524,288
  float* Earr = Lend + 524288;         // 524,288
  unsigned short* BWb  = (unsigned short*)(Earr + 524288);  // 32,768 us
  unsigned short* Wd1b = BWb + 32768;                       // 65,536 us
  unsigned short* Wd2b = Wd1b + 65536;                      // 65,536 us

  // d_out staging: [0,16MB) ubuf bf16; [16MB,48MB) w1 bf16; final fp32 overwrites
  unsigned short* ubuf = (unsigned short*)d_out;            // 65536x128 bf16
  unsigned short* w1   = ubuf + 8388608;                    // 65536x256 bf16
  unsigned short* w2   = (unsigned short*)Cbuf;             // 65536x256 bf16 (Cbuf dead after phase3)

  const dim3 tblk(32, 8), tgrid(8, 8);

  transpose256<<<tgrid, tblk, 0, stream>>>(A_W, AT);
  encoder_kernel<<<32, 256, 0, stream>>>(in, We1, be1, We2, be2, z0);
  extract_u<<<8192, 256, 0, stream>>>(in, ubuf);
  f2bf_kernel<<<32, 256, 0, stream>>>(B_W, BWb, 32768);
  f2bf_kernel<<<64, 256, 0, stream>>>(Wd1, Wd1b, 65536);
  f2bf_kernel<<<64, 256, 0, stream>>>(Wd2, Wd2b, 65536);

  // c_t = u @ B_W^T + B_b + A_b -> Cbuf (fp32)
  gemm_mfma<<<dim3(512, 2), 256, 0, stream>>>(ubuf, ALEN, BWb, A_b, B_b, 0, 0, Cbuf);

  // P = A^32 by repeated squaring, dual-output (X^2, (X^2)^T) per launch
  gemm_sq<<<dim3(4, 4), 256, 0, stream>>>(A_W, AT, Pa, PaT);   // A^2
  gemm_sq<<<dim3(4, 4), 256, 0, stream>>>(Pa, PaT, Pb, PbT);   // A^4
  gemm_sq<<<dim3(4, 4), 256, 0, stream>>>(Pb, PbT, Pa, PaT);   // A^8
  gemm_sq<<<dim3(4, 4), 256, 0, stream>>>(Pa, PaT, Pb, PbT);   // A^16
  gemm_sq<<<dim3(4, 4), 256, 0, stream>>>(Pb, PbT, Pa, PT);    // A^32; PT = (A^32)^T

  phase_kernel<<<256, 512, 0, stream>>>(AT, Cbuf, nullptr, Lend, nullptr);
  boundary_kernel<<<32, 512, 0, stream>>>(PT, z0, Lend, Earr);
  phase_kernel<<<256, 512, 0, stream>>>(AT, Cbuf, Earr, nullptr, w1);

  // dec1: w2 = bf16(inv_leaky(w1 @ Wd1^T + bd1))
  gemm_mfma<<<dim3(512, 2), 256, 0, stream>>>(w1, D256, Wd1b, bd1, nullptr, 1, 1, w2);
  // dec2: y = w2 @ Wd2^T + bd2 -> d_out (fp32)
  gemm_mfma<<<dim3(512, 2), 256, 0, stream>>>(w2, D256, Wd2b, bd2, nullptr, 0, 0, out);
}